// Round 1
// 276.499 us; speedup vs baseline: 1.0066x; 1.0066x over previous
//
#include <hip/hip_runtime.h>
#include <hip/hip_bf16.h>

#define BATCH 16
#define CIN 64
#define COUT 64
#define HH 160
#define WW 160
#define HP 162
#define WP 162

typedef __attribute__((ext_vector_type(8))) __bf16 bf16x8;
typedef __attribute__((ext_vector_type(4))) float f32x4;
typedef __attribute__((ext_vector_type(8))) unsigned short ushort8;

typedef __attribute__((address_space(1))) const unsigned int gu32;
typedef __attribute__((address_space(3))) unsigned int lu32;

// ---------------------------------------------------------------------------
// Pass 1 (v4): x (NCHW fp32) -> xs (B, 162, 162, 64) bf16, shift folded in,
// PLUS weight cvt folded into the same launch (blocks >= BATCH*HP).
// Load phase unchanged (coalesced f32x4, rotated LDS write).
// Store phase rewritten: each thread owns a FIXED 8-channel group
// (cg = tid&7, channels cg*8..cg*8+7) so dx/rot are hoisted; per iteration it
// does 8 independent LDS reads (2-way bank aliasing = free) and ONE 16B
// ushort8 store (1024 B/wave fully coalesced). 6 iterations vs 41 before.
// ---------------------------------------------------------------------------
__global__ __launch_bounds__(256) void prep(const float* __restrict__ x,
                                            const float* __restrict__ w,
                                            unsigned short* __restrict__ xs,
                                            unsigned short* __restrict__ wb) {
  __shared__ float lds[64 * 160];  // 40 KB

  if (blockIdx.x >= BATCH * HP) {
    // ---- weight cvt: w (O,C,3,3) fp32 -> wb[tap][o][c] bf16 ----
    int e = (blockIdx.x - BATCH * HP) * 256 + threadIdx.x;
    if (e < 9 * 64 * 64) {
      int tap = e >> 12;
      int o = (e >> 6) & 63;
      int c = e & 63;
      float v = w[((size_t)(o * 64 + c)) * 9 + tap];
      __hip_bfloat16 h = __float2bfloat16(v);
      wb[e] = *reinterpret_cast<unsigned short*>(&h);
    }
    return;
  }

  int y = blockIdx.x % HP;
  int b = blockIdx.x / HP;
  int tid = threadIdx.x;

  // ---- load: global (coalesced along W) -> LDS rotated ----
#pragma unroll
  for (int it = 0; it < 10; ++it) {
    int idx = it * 256 + tid;  // 0..2559 = 64 ch x 40 f32x4
    int c = idx / 40;
    int j = idx - c * 40;
    int cm = c % 5;
    int dx = (cm == 1) ? 1 : ((cm == 3) ? -1 : 0);
    int dy = (cm == 2) ? 1 : ((cm == 4) ? -1 : 0);
    int yy = y - dy;  // source row (1..160 valid)
    f32x4 v = {0.f, 0.f, 0.f, 0.f};
    if (yy >= 1 && yy <= HH)
      v = *reinterpret_cast<const f32x4*>(
          x + (((size_t)(b * CIN + c)) * HH + (size_t)(yy - 1)) * WW + j * 4);
    int rot = (c & 31) + dx;
    if (rot < 0) rot += 160;
    int p0 = 4 * j + rot;  // < 320
#pragma unroll
    for (int e = 0; e < 4; ++e) {
      int p = p0 + e;
      if (p >= 160) p -= 160;
      lds[c * 160 + p] = v[e];
    }
  }
  __syncthreads();

  // ---- store: fixed 8-channel group per thread, 16B stores ----
  int cg = tid & 7;   // channel group: channels cg*8 .. cg*8+7
  int xr = tid >> 3;  // xi = it*32 + xr
  int dxe[8], rote[8], rowb[8];
#pragma unroll
  for (int e = 0; e < 8; ++e) {
    int c = cg * 8 + e;
    int cm = c % 5;
    int dx = (cm == 1) ? 1 : ((cm == 3) ? -1 : 0);
    int rot = (c & 31) + dx;
    if (rot < 0) rot += 160;
    dxe[e] = dx;
    rote[e] = rot;
    rowb[e] = c * 160;
  }
  size_t obase = ((size_t)(b * HP + y) * WP) * CIN + cg * 8;
#pragma unroll
  for (int it = 0; it < 6; ++it) {
    int xi = it * 32 + xr;
    if (xi < WP) {
      ushort8 val;
#pragma unroll
      for (int e = 0; e < 8; ++e) {
        int xx = xi - dxe[e] - 1;  // source x (0..159 valid)
        float v = 0.f;
        if (xx >= 0 && xx < WW) {
          int p = rote[e] + xx;
          if (p >= 160) p -= 160;
          v = lds[rowb[e] + p];
        }
        __hip_bfloat16 h = __float2bfloat16(v);
        val[e] = *reinterpret_cast<unsigned short*>(&h);
      }
      *reinterpret_cast<ushort8*>(xs + obase + (size_t)xi * CIN) = val;
    }
  }
}

// ---------------------------------------------------------------------------
// Pass 2 (v4): implicit-GEMM conv, tile = 8 rows x 32 cols x 64 ochans.
//  - staging via __builtin_amdgcn_global_load_lds width=16 (async, no VGPR
//    roundtrip). LDS is unpadded [pixel][64ch] (340*128 B = 43,520 B), which
//    is linear in lane order as gload_lds requires; the bank-spread is done
//    with a 16B-chunk XOR swizzle applied BOTH on the global source address
//    (inverse) and on the ds_read address (rule #21: both sides, same
//    involution): dest chunk j of pixel p holds global chunk j^(p&7).
//  - software pipeline in the fully-unrolled tap loop: B (weights, L2) is
//    prefetched 2 taps ahead (Bb[t%3]), A (LDS) 1 tap ahead (Ab[t&1]) —
//    all indices compile-time after unroll (no scratch, rule #20).
// MFMA mapping unchanged (harness-verified): D[row=q*4+reg][col=l15],
// x = x0 + (mt&1)*16 + q*4 + reg, o = nt*16 + l15.
// ---------------------------------------------------------------------------
__global__ __launch_bounds__(256, 3) void conv_mfma(const unsigned short* __restrict__ xs,
                                                    const unsigned short* __restrict__ wb,
                                                    float* __restrict__ out) {
  __shared__ __align__(16) unsigned short lds_in[340 * 64];  // 43,520 B

  int tj = blockIdx.x, ti = blockIdx.y, b = blockIdx.z;
  int tid = threadIdx.x;
  int y0 = ti * 8, x0 = tj * 32;

  // ---- async stage: 2720 16B chunks = 340 pixels x 8, swizzled source ----
  const size_t xs_b = (size_t)b * HP * WP * CIN;
#pragma unroll
  for (int k = 0; k < 11; ++k) {
    int u = k * 256 + tid;  // chunk index
    if (u < 2720) {
      int p = u >> 3;                 // pixel 0..339
      int j = (u & 7) ^ (p & 7);      // source chunk (inverse swizzle)
      int pr = p / 34, pc = p - pr * 34;
      const unsigned short* src =
          xs + xs_b + ((size_t)(y0 + pr) * WP + (size_t)(x0 + pc)) * CIN + j * 8;
      // dest: wave-uniform base; HW adds lane*16
      __builtin_amdgcn_global_load_lds((gu32*)src, (lu32*)&lds_in[(u & ~63) * 8],
                                       16, 0, 0);
    }
  }
  __syncthreads();

  int wv = tid >> 6;
  int lane = tid & 63;
  int l15 = lane & 15;
  int q = lane >> 4;
  int pb = 2 * wv * 34 + l15;  // per-lane pixel base
  const unsigned short* bbase = wb + l15 * 64 + q * 8;

  f32x4 acc[4][4];
#pragma unroll
  for (int a = 0; a < 4; ++a)
#pragma unroll
    for (int bb2 = 0; bb2 < 4; ++bb2) acc[a][bb2] = (f32x4){0.f, 0.f, 0.f, 0.f};

  bf16x8 Ab[2][4];  // A fragments, 1 tap ahead
  bf16x8 Bb[3][4];  // B fragments, 2 taps ahead

#define LOAD_B(buf, t)                                                        \
  {                                                                           \
    const int ch_ = (t) / 9, tap_ = (t) % 9;                                  \
    _Pragma("unroll") for (int nt = 0; nt < 4; ++nt)                          \
        Bb[buf][nt] = *reinterpret_cast<const bf16x8*>(                       \
            bbase + tap_ * 4096 + nt * 1024 + ch_ * 32);                      \
  }

#define LOAD_A(buf, t)                                                        \
  {                                                                           \
    const int ch_ = (t) / 9, ky_ = ((t) % 9) / 3, kx_ = (t) % 3;              \
    _Pragma("unroll") for (int mt = 0; mt < 4; ++mt) {                        \
      int pix = pb + (((mt >> 1) + ky_) * 34 + kx_ + (mt & 1) * 16);          \
      int chunk = (ch_ * 4 + q) ^ (pix & 7);                                  \
      Ab[buf][mt] =                                                           \
          *reinterpret_cast<const bf16x8*>(&lds_in[pix * 64 + chunk * 8]);    \
    }                                                                         \
  }

  LOAD_B(0, 0);
  LOAD_B(1, 1);
  LOAD_A(0, 0);
#pragma unroll
  for (int t = 0; t < 18; ++t) {  // t = ch*9 + ky*3 + kx
    if (t + 2 < 18) LOAD_B((t + 2) % 3, t + 2);
    if (t + 1 < 18) LOAD_A((t + 1) & 1, t + 1);
#pragma unroll
    for (int mt = 0; mt < 4; ++mt)
#pragma unroll
      for (int nt = 0; nt < 4; ++nt)
        acc[mt][nt] = __builtin_amdgcn_mfma_f32_16x16x32_bf16(
            Ab[t & 1][mt], Bb[t % 3][nt], acc[mt][nt], 0, 0, 0);
  }
#undef LOAD_A
#undef LOAD_B

  // ---- epilogue: x = x0 + (mt&1)*16 + q*4 (+reg), row i = y0 + 2wv + (mt>>1)
#pragma unroll
  for (int mt = 0; mt < 4; ++mt) {
    int i = y0 + 2 * wv + (mt >> 1);
    int xo = x0 + (mt & 1) * 16 + q * 4;
#pragma unroll
    for (int nt = 0; nt < 4; ++nt) {
      int o = nt * 16 + l15;
      *reinterpret_cast<f32x4*>(out + ((size_t)(b * COUT + o) * HH + (size_t)i) * WW + xo) =
          acc[mt][nt];
    }
  }
}

extern "C" void kernel_launch(void* const* d_in, const int* in_sizes, int n_in,
                              void* d_out, int out_size, void* d_ws, size_t ws_size,
                              hipStream_t stream) {
  const float* x = (const float*)d_in[0];
  const float* w = (const float*)d_in[1];
  float* out = (float*)d_out;

  unsigned short* xs = (unsigned short*)d_ws;  // 16*162*162*64 bf16 = 53.7 MB
  unsigned short* wb = (unsigned short*)((char*)d_ws + (size_t)BATCH * HP * WP * CIN * 2);

  // prep: 2592 shift blocks + 144 weight-cvt blocks in one launch
  hipLaunchKernelGGL(prep, dim3(BATCH * HP + 144), dim3(256), 0, stream, x, w, xs, wb);
  hipLaunchKernelGGL(conv_mfma, dim3(5, 20, BATCH), dim3(256), 0, stream, xs, wb, out);
}

// Round 3
// 226.514 us; speedup vs baseline: 1.2287x; 1.2207x over previous
//
#include <hip/hip_runtime.h>
#include <hip/hip_bf16.h>

#define BATCH 16
#define CIN 64
#define COUT 64
#define HH 160
#define WW 160
#define HP 162
#define WP 162

#define ABUF 21760  // shorts per A buffer: 340 pixels * 64 ch (43,520 B)

typedef __attribute__((ext_vector_type(8))) __bf16 bf16x8;
typedef __attribute__((ext_vector_type(4))) float f32x4;
typedef __attribute__((ext_vector_type(8))) unsigned short ushort8;

typedef __attribute__((address_space(1))) const unsigned int gu32;
typedef __attribute__((address_space(3))) unsigned int lu32;

// ---------------------------------------------------------------------------
// Pass 1 (unchanged, harness-verified): x (NCHW fp32) -> xs (B,162,162,64)
// bf16 with shift folded in; weight cvt folded into trailing blocks.
// ---------------------------------------------------------------------------
__global__ __launch_bounds__(256) void prep(const float* __restrict__ x,
                                            const float* __restrict__ w,
                                            unsigned short* __restrict__ xs,
                                            unsigned short* __restrict__ wb) {
  __shared__ float lds[64 * 160];  // 40 KB

  if (blockIdx.x >= BATCH * HP) {
    int e = (blockIdx.x - BATCH * HP) * 256 + threadIdx.x;
    if (e < 9 * 64 * 64) {
      int tap = e >> 12;
      int o = (e >> 6) & 63;
      int c = e & 63;
      float v = w[((size_t)(o * 64 + c)) * 9 + tap];
      __hip_bfloat16 h = __float2bfloat16(v);
      wb[e] = *reinterpret_cast<unsigned short*>(&h);
    }
    return;
  }

  int y = blockIdx.x % HP;
  int b = blockIdx.x / HP;
  int tid = threadIdx.x;

#pragma unroll
  for (int it = 0; it < 10; ++it) {
    int idx = it * 256 + tid;  // 0..2559 = 64 ch x 40 f32x4
    int c = idx / 40;
    int j = idx - c * 40;
    int cm = c % 5;
    int dx = (cm == 1) ? 1 : ((cm == 3) ? -1 : 0);
    int dy = (cm == 2) ? 1 : ((cm == 4) ? -1 : 0);
    int yy = y - dy;  // source row (1..160 valid)
    f32x4 v = {0.f, 0.f, 0.f, 0.f};
    if (yy >= 1 && yy <= HH)
      v = *reinterpret_cast<const f32x4*>(
          x + (((size_t)(b * CIN + c)) * HH + (size_t)(yy - 1)) * WW + j * 4);
    int rot = (c & 31) + dx;
    if (rot < 0) rot += 160;
    int p0 = 4 * j + rot;
#pragma unroll
    for (int e = 0; e < 4; ++e) {
      int p = p0 + e;
      if (p >= 160) p -= 160;
      lds[c * 160 + p] = v[e];
    }
  }
  __syncthreads();

  int cg = tid & 7;
  int xr = tid >> 3;
  int dxe[8], rote[8], rowb[8];
#pragma unroll
  for (int e = 0; e < 8; ++e) {
    int c = cg * 8 + e;
    int cm = c % 5;
    int dx = (cm == 1) ? 1 : ((cm == 3) ? -1 : 0);
    int rot = (c & 31) + dx;
    if (rot < 0) rot += 160;
    dxe[e] = dx;
    rote[e] = rot;
    rowb[e] = c * 160;
  }
  size_t obase = ((size_t)(b * HP + y) * WP) * CIN + cg * 8;
#pragma unroll
  for (int it = 0; it < 6; ++it) {
    int xi = it * 32 + xr;
    if (xi < WP) {
      ushort8 val;
#pragma unroll
      for (int e = 0; e < 8; ++e) {
        int xx = xi - dxe[e] - 1;
        float v = 0.f;
        if (xx >= 0 && xx < WW) {
          int p = rote[e] + xx;
          if (p >= 160) p -= 160;
          v = lds[rowb[e] + p];
        }
        __hip_bfloat16 h = __float2bfloat16(v);
        val[e] = *reinterpret_cast<unsigned short*>(&h);
      }
      *reinterpret_cast<ushort8*>(xs + obase + (size_t)xi * CIN) = val;
    }
  }
}

// ---------------------------------------------------------------------------
// Pass 2 (v6): PERSISTENT pipelined implicit-GEMM conv, weights in LDS.
//  - 256 blocks (1/CU), each owns 6-7 tiles of 8x32x64.
//  - LDS: A double-buffer (2 x 43,520 B, DISTINCT static arrays so alias
//    analysis proves gload_lds(WBUF) independent of ds_read(RBUF)) + full
//    weight tensor (73,728 B) staged ONCE. Total 160,768 B (fits 160 KiB).
//  - Inner 18-tap loop has ZERO VMEM: A and B both ds_read (lgkmcnt only),
//    so next-tile stage loads stay in flight across the WHOLE compute phase;
//    the single vmcnt(0) drain sits at the per-tile __syncthreads where the
//    data is needed anyway (R2 bug fixed: no register-buffer collision, both
//    A and B are 1-tap-ahead ping-pong on (tt&1) vs (tt+1)&1).
//  - B LDS layout gets the same chunk-XOR involution as A: lds chunk
//    j of row o holds global chunk j^(o&7); read chunk (ch*4+q)^(l15&7).
//    (Without it, l15-lanes at 128 B stride = 16-way bank conflict.)
//  - XCD-chunked tile map: block k -> tile0=(k&7)*32+(k>>3), tiles
//    tile0+256*i. Bijective; each XCD covers a contiguous 32-tile band.
// MFMA mapping unchanged (harness-verified): D[row=q*4+reg][col=l15],
// x = x0 + (mt&1)*16 + q*4 + reg, o = nt*16 + l15.
// ---------------------------------------------------------------------------
__global__ __launch_bounds__(256, 1) void conv_mfma(const unsigned short* __restrict__ xs,
                                                    const unsigned short* __restrict__ wb,
                                                    float* __restrict__ out) {
  __shared__ __align__(16) unsigned short lds_a[ABUF];       // 43,520 B
  __shared__ __align__(16) unsigned short lds_b[ABUF];       // 43,520 B
  __shared__ __align__(16) unsigned short lds_w[9 * 64 * 64];  // 73,728 B

  int tid = threadIdx.x;
  int blk = blockIdx.x;
  int tile0 = (blk & 7) * 32 + (blk >> 3);  // XCD-chunked, bijective (256%8==0)
  int ntiles = (tile0 < 64) ? 7 : 6;        // 64*7 + 192*6 = 1600

  int wv = tid >> 6;
  int lane = tid & 63;
  int l15 = lane & 15;
  int q = lane >> 4;

  // tile-invariant per-thread A-staging source offsets (shorts)
  int goff[11];
#pragma unroll
  for (int r = 0; r < 11; ++r) {
    int u = r * 256 + tid;          // chunk index 0..2815 (valid < 2720)
    int p = u >> 3;                 // pixel
    int j = (u & 7) ^ (p & 7);      // source chunk (inverse swizzle)
    int pr = p / 34, pc = p - pr * 34;
    goff[r] = (pr * WP + pc) * CIN + j * 8;
  }

  // per-lane B bases in lds_w (shorts): chunk' = (ch*4+q) ^ (l15&7)
  int bw0 = l15 * 64 + ((q ^ (l15 & 7)) * 8);        // ch = 0
  int bw1 = l15 * 64 + (((4 + q) ^ (l15 & 7)) * 8);  // ch = 1

#define STAGE_TO(BUFARR, T_)                                                   \
  {                                                                            \
    int sb_ = (T_) / 100;                                                      \
    int srr_ = (T_) - sb_ * 100;                                               \
    int sti_ = srr_ / 5, stj_ = srr_ - sti_ * 5;                               \
    const unsigned short* srcb_ = xs +                                         \
        ((size_t)sb_ * HP + (size_t)(sti_ * 8)) * WP * CIN +                   \
        (size_t)(stj_ * 32) * CIN;                                             \
    unsigned short* dst0_ = (BUFARR) + wv * 512;                               \
    _Pragma("unroll") for (int r = 0; r < 10; ++r)                             \
        __builtin_amdgcn_global_load_lds((gu32*)(srcb_ + goff[r]),             \
                                         (lu32*)(dst0_ + r * 2048), 16, 0, 0); \
    if (tid < 160)                                                             \
      __builtin_amdgcn_global_load_lds((gu32*)(srcb_ + goff[10]),              \
                                       (lu32*)(dst0_ + 10 * 2048), 16, 0, 0);  \
  }

#define LOAD_A(RBUF, bufp, tt)                                                 \
  {                                                                            \
    const int ch_ = (tt) / 9, ky_ = ((tt) % 9) / 3, kx_ = (tt) % 3;            \
    _Pragma("unroll") for (int mt = 0; mt < 4; ++mt) {                         \
      int pix = 2 * wv * 34 + l15 +                                            \
                (((mt >> 1) + ky_) * 34 + kx_ + (mt & 1) * 16);                \
      int chunk = (ch_ * 4 + q) ^ (pix & 7);                                   \
      Ab[bufp][mt] =                                                           \
          *reinterpret_cast<const bf16x8*>(&(RBUF)[pix * 64 + chunk * 8]);     \
    }                                                                          \
  }

#define LOAD_BW(bufp, tt)                                                      \
  {                                                                            \
    const int ch_ = (tt) / 9, tap_ = (tt) % 9;                                 \
    _Pragma("unroll") for (int nt = 0; nt < 4; ++nt)                           \
        Bb[bufp][nt] = *reinterpret_cast<const bf16x8*>(                       \
            &lds_w[tap_ * 4096 + nt * 1024 + (ch_ ? bw1 : bw0)]);              \
  }

#define TILE_BODY(I_, RBUF, WBUF)                                              \
  {                                                                            \
    int t_ = tile0 + 256 * (I_);                                               \
    int b_ = t_ / 100;                                                         \
    int rr_ = t_ - b_ * 100;                                                   \
    int ti_ = rr_ / 5, tj_ = rr_ - ti_ * 5;                                    \
    int y0_ = ti_ * 8, x0_ = tj_ * 32;                                         \
    if ((I_) + 1 < ntiles) STAGE_TO(WBUF, tile0 + 256 * ((I_) + 1));           \
    _Pragma("unroll") for (int a_ = 0; a_ < 4; ++a_)                           \
      _Pragma("unroll") for (int c2_ = 0; c2_ < 4; ++c2_)                      \
        acc[a_][c2_] = (f32x4){0.f, 0.f, 0.f, 0.f};                            \
    LOAD_A(RBUF, 0, 0);                                                        \
    LOAD_BW(0, 0);                                                             \
    _Pragma("unroll") for (int tt = 0; tt < 18; ++tt) {                        \
      if (tt + 1 < 18) {                                                       \
        LOAD_A(RBUF, (tt + 1) & 1, tt + 1);                                    \
        LOAD_BW((tt + 1) & 1, tt + 1);                                         \
      }                                                                        \
      _Pragma("unroll") for (int mt = 0; mt < 4; ++mt)                         \
        _Pragma("unroll") for (int nt = 0; nt < 4; ++nt)                       \
          acc[mt][nt] = __builtin_amdgcn_mfma_f32_16x16x32_bf16(               \
              Ab[tt & 1][mt], Bb[tt & 1][nt], acc[mt][nt], 0, 0, 0);           \
    }                                                                          \
    __syncthreads();                                                           \
    _Pragma("unroll") for (int mt = 0; mt < 4; ++mt) {                         \
      int orow_ = y0_ + 2 * wv + (mt >> 1);                                    \
      int xo_ = x0_ + (mt & 1) * 16 + q * 4;                                   \
      _Pragma("unroll") for (int nt = 0; nt < 4; ++nt) {                       \
        int o_ = nt * 16 + l15;                                                \
        *reinterpret_cast<f32x4*>(                                             \
            out + ((size_t)(b_ * COUT + o_) * HH + (size_t)orow_) * WW + xo_) = \
            acc[mt][nt];                                                       \
      }                                                                        \
    }                                                                          \
  }

  f32x4 acc[4][4];
  bf16x8 Ab[2][4];
  bf16x8 Bb[2][4];

  // ---- prologue: stage weights (once) + tile0, one barrier ----
  // weights: 4608 chunks = 18 iters * 256 thr; lds chunk u holds global
  // chunk (u&7)^(orow&7) of o-row orow=u>>3 (the read-side involution).
  for (int r = 0; r < 18; ++r) {
    int u = r * 256 + tid;
    int orow = u >> 3;
    int jj = (u & 7) ^ (orow & 7);
    __builtin_amdgcn_global_load_lds((gu32*)(wb + orow * 64 + jj * 8),
                                     (lu32*)(lds_w + (u & ~63) * 8), 16, 0, 0);
  }
  STAGE_TO(lds_a, tile0);
  __syncthreads();

  for (int i = 0; i < ntiles; i += 2) {
    TILE_BODY(i, lds_a, lds_b);
    if (i + 1 < ntiles) TILE_BODY(i + 1, lds_b, lds_a);
  }

#undef TILE_BODY
#undef LOAD_BW
#undef LOAD_A
#undef STAGE_TO
}

extern "C" void kernel_launch(void* const* d_in, const int* in_sizes, int n_in,
                              void* d_out, int out_size, void* d_ws, size_t ws_size,
                              hipStream_t stream) {
  const float* x = (const float*)d_in[0];
  const float* w = (const float*)d_in[1];
  float* out = (float*)d_out;

  unsigned short* xs = (unsigned short*)d_ws;  // 16*162*162*64 bf16 = 53.7 MB
  unsigned short* wb = (unsigned short*)((char*)d_ws + (size_t)BATCH * HP * WP * CIN * 2);

  hipLaunchKernelGGL(prep, dim3(BATCH * HP + 144), dim3(256), 0, stream, x, w, xs, wb);
  hipLaunchKernelGGL(conv_mfma, dim3(256), dim3(256), 0, stream, xs, wb, out);
}